// Round 12
// baseline (583.816 us; speedup 1.0000x reference)
//
#include <hip/hip_runtime.h>
#include <hip/hip_bf16.h>
#include <math.h>

#define HD 128   // hidden dim = H*C
#define NH 4     // heads
#define CC 32    // channels per head

typedef __attribute__((ext_vector_type(8))) short short8;
typedef __attribute__((ext_vector_type(4))) float f32x4;

__device__ __forceinline__ float leaky(float x) { return x > 0.f ? x : 0.01f * x; }

// f32 -> bf16 round-to-nearest-even (finite values)
__device__ __forceinline__ ushort bf16_rne(float f) {
    unsigned u = __float_as_uint(f);
    return (ushort)((u + 0x7fffu + ((u >> 16) & 1u)) >> 16);
}
__device__ __forceinline__ float bf16_f(ushort h) {
    return __uint_as_float(((unsigned)h) << 16);
}

// Wfrag layout: [mg(12)][ct(8)][kk(4)][lane(64)][j(8)] ushort, hi half then lo
// half at +WFRAG_HALF. mg = layer*4 + mat. B-frag mapping (16x16x32):
// col = ct*16+(lane&15), k = kk*32+(lane>>4)*8+j.   (verified: r5/r7/r8 passed)
#define WFRAG_HALF (12 * 32 * 64 * 8)

// ---------------------------------------------------------------------------
// Convert W (f32, [3][128][128] x 4 matrices) into bf16 hi/lo B-fragments.
// ---------------------------------------------------------------------------
__global__ __launch_bounds__(256) void conv_w(
    const float* __restrict__ Wq, const float* __restrict__ Wk,
    const float* __restrict__ Wv, const float* __restrict__ Wsk,
    ushort* __restrict__ frag)
{
    int tid = blockIdx.x * 256 + threadIdx.x;
    if (tid >= 12 * 8 * 4 * 64) return;
    int lane = tid & 63;
    int kk = (tid >> 6) & 3;
    int ct = (tid >> 8) & 7;
    int mg = tid >> 11;            // 0..11
    int l = mg >> 2, m = mg & 3;
    const float* src = ((m == 0) ? Wq : (m == 1) ? Wk : (m == 2) ? Wv : Wsk)
                       + (size_t)l * HD * HD;
    int col = ct * 16 + (lane & 15);
    int k0 = kk * 32 + (lane >> 4) * 8;
    ushort* dst = frag + (size_t)tid * 8;
#pragma unroll
    for (int j = 0; j < 8; ++j) {
        float w = src[(size_t)(k0 + j) * HD + col];
        ushort h = bf16_rne(w);
        dst[j] = h;
        dst[WFRAG_HALF + j] = bf16_rne(w - bf16_f(h));
    }
}

// ---------------------------------------------------------------------------
// MFMA GEMM, split-bf16 (hh+hl+lh). 512 threads = 8 waves.
// Block = 64 rows. Wave = (p, h): p in 0..3 owns cols p*32..p*32+31, h in 0..1
// owns rows h*32..h*32+31. W-frags register-resident. Epilogue bounces acc
// through wave-private LDS so stores are full aligned 128B lines (r8 fix).
// ---------------------------------------------------------------------------
__global__ __launch_bounds__(512) void gemm4_mfma(
    const float* __restrict__ X, const ushort* __restrict__ Wfrag,
    const float* __restrict__ bq, const float* __restrict__ bk,
    const float* __restrict__ bv, const float* __restrict__ bsk,
    float* __restrict__ Oq, float* __restrict__ Ok,
    float* __restrict__ Ov, float* __restrict__ Osk,
    int layer, int N)
{
    __shared__ __align__(16) ushort Xh[64 * HD];   // 16 KB
    __shared__ __align__(16) ushort Xl[64 * HD];   // 16 KB
    __shared__ __align__(16) float  Ot[8][16 * 36]; // 18 KB wave-private scratch

    int t = threadIdx.x;
    int row0 = blockIdx.x * 64;

    // ---- stage X tile as hi/lo bf16, swizzled: byte ^= (row&7)<<4 ----
#pragma unroll
    for (int i = 0; i < 4; ++i) {
        int idx = t + i * 512;           // 0..2047
        int r = idx >> 5;                // 0..63
        int c4 = (idx & 31) * 4;         // first k of this float4
        int gr = row0 + r;
        float4 xv = (gr < N) ? *(const float4*)(X + (size_t)gr * HD + c4)
                             : make_float4(0.f, 0.f, 0.f, 0.f);
        ushort h0 = bf16_rne(xv.x), h1 = bf16_rne(xv.y),
               h2 = bf16_rne(xv.z), h3 = bf16_rne(xv.w);
        ushort l0 = bf16_rne(xv.x - bf16_f(h0)), l1 = bf16_rne(xv.y - bf16_f(h1)),
               l2 = bf16_rne(xv.z - bf16_f(h2)), l3 = bf16_rne(xv.w - bf16_f(h3));
        int off = r * 256 + c4 * 2;                 // byte offset, 8B-aligned
        int swz = off ^ ((r & 7) << 4);
        *(ushort4*)((char*)Xh + swz) = make_ushort4(h0, h1, h2, h3);
        *(ushort4*)((char*)Xl + swz) = make_ushort4(l0, l1, l2, l3);
    }
    __syncthreads();

    int w = t >> 6;                  // wave id
    int p = w & 3;                   // col pair: cols p*32..p*32+31
    int h = w >> 2;                  // row half: rows h*32..h*32+31
    int lane = t & 63;
    int col16 = lane & 15;
    int quad = lane >> 4;
    float* scratch = Ot[w];

#pragma unroll
    for (int mm = 0; mm < 2; ++mm) {
        int mat = blockIdx.y * 2 + mm;
        const float* b = (mat == 0) ? bq : (mat == 1) ? bk : (mat == 2) ? bv : bsk;
        float* O = (mat == 0) ? Oq : (mat == 1) ? Ok : (mat == 2) ? Ov : Osk;
        int mg = layer * 4 + mat;

        // ---- load this wave's 2 col-tiles' W fragments into registers ----
        short8 bh[2][4], bl[2][4];
#pragma unroll
        for (int cl = 0; cl < 2; ++cl) {
            int ct = p * 2 + cl;
#pragma unroll
            for (int kk = 0; kk < 4; ++kk) {
                const ushort* wp = Wfrag + ((size_t)((mg * 8 + ct) * 4 + kk) * 64 + lane) * 8;
                bh[cl][kk] = *(const short8*)wp;
                bl[cl][kk] = *(const short8*)(wp + WFRAG_HALF);
            }
        }
        float bcol0 = b[(p * 2 + 0) * 16 + col16];
        float bcol1 = b[(p * 2 + 1) * 16 + col16];

#pragma unroll
        for (int mtl = 0; mtl < 2; ++mtl) {
            int arow = h * 32 + mtl * 16 + col16;    // A row for this lane
            int abase = arow * 256;
            int aswz = (arow & 7) << 4;
            f32x4 c0a = {0.f,0.f,0.f,0.f}, c0b = {0.f,0.f,0.f,0.f}, c0c = {0.f,0.f,0.f,0.f};
            f32x4 c1a = {0.f,0.f,0.f,0.f}, c1b = {0.f,0.f,0.f,0.f}, c1c = {0.f,0.f,0.f,0.f};
#pragma unroll
            for (int kk = 0; kk < 4; ++kk) {
                int koff = abase + kk * 64 + quad * 16;   // bytes
                short8 ah = *(const short8*)((const char*)Xh + (koff ^ aswz));
                short8 al = *(const short8*)((const char*)Xl + (koff ^ aswz));
                c0a = __builtin_amdgcn_mfma_f32_16x16x32_bf16(ah, bh[0][kk], c0a, 0, 0, 0);
                c0b = __builtin_amdgcn_mfma_f32_16x16x32_bf16(ah, bl[0][kk], c0b, 0, 0, 0);
                c0c = __builtin_amdgcn_mfma_f32_16x16x32_bf16(al, bh[0][kk], c0c, 0, 0, 0);
                c1a = __builtin_amdgcn_mfma_f32_16x16x32_bf16(ah, bh[1][kk], c1a, 0, 0, 0);
                c1b = __builtin_amdgcn_mfma_f32_16x16x32_bf16(ah, bl[1][kk], c1b, 0, 0, 0);
                c1c = __builtin_amdgcn_mfma_f32_16x16x32_bf16(al, bh[1][kk], c1c, 0, 0, 0);
            }
            // ---- epilogue via wave-private LDS -> full-line stores ----
#pragma unroll
            for (int i = 0; i < 4; ++i) {
                int rr = quad * 4 + i;
                scratch[rr * 36 + col16]      = c0a[i] + c0b[i] + c0c[i] + bcol0;
                scratch[rr * 36 + 16 + col16] = c1a[i] + c1b[i] + c1c[i] + bcol1;
            }
#pragma unroll
            for (int s = 0; s < 2; ++s) {
                int row = s * 8 + (lane >> 3);
                int c4 = (lane & 7) * 4;
                float4 v = *(const float4*)(&scratch[row * 36 + c4]);
                int gr = row0 + h * 32 + mtl * 16 + row;
                if (gr < N)
                    *(float4*)(O + (size_t)gr * HD + p * 32 + c4) = v;
            }
        }
    }
}

// ---------------------------------------------------------------------------
// CSR build step 1: deg[dst]++ per edge
// ---------------------------------------------------------------------------
__global__ __launch_bounds__(256) void count_deg(
    const int* __restrict__ ei, int* __restrict__ deg, int E)
{
    int e = blockIdx.x * 256 + threadIdx.x;
    if (e < E) atomicAdd(&deg[ei[E + e]], 1);
}

// ---------------------------------------------------------------------------
// CSR build step 2: exclusive scan of deg -> off (N+1), duplicate into cursor.
// ---------------------------------------------------------------------------
__global__ __launch_bounds__(1024) void scan_kernel(
    const int* __restrict__ deg, int* __restrict__ off,
    int* __restrict__ cursor, int N)
{
    __shared__ int wsum[16];
    __shared__ int carry_s;
    int tid = threadIdx.x;
    int lane = tid & 63;
    int w = tid >> 6;
    if (tid == 0) carry_s = 0;
    __syncthreads();
    for (int base = 0; base < N; base += 1024) {
        int idx = base + tid;
        int x = (idx < N) ? deg[idx] : 0;
        int val = x;
#pragma unroll
        for (int s = 1; s < 64; s <<= 1) {
            int t = __shfl_up(val, s);
            if (lane >= s) val += t;
        }
        if (lane == 63) wsum[w] = val;
        __syncthreads();
        if (w == 0) {
            int t = (lane < 16) ? wsum[lane] : 0;
#pragma unroll
            for (int s = 1; s < 16; s <<= 1) {
                int u = __shfl_up(t, s);
                if (lane >= s) t += u;
            }
            if (lane < 16) wsum[lane] = t;  // inclusive wave totals
        }
        __syncthreads();
        int carry = carry_s;
        int wexcl = (w > 0) ? wsum[w - 1] : 0;
        int excl = carry + wexcl + (val - x);
        if (idx < N) { off[idx] = excl; cursor[idx] = excl; }
        __syncthreads();
        if (tid == 0) carry_s = carry + wsum[15];
        __syncthreads();
    }
    if (threadIdx.x == 0) off[N] = carry_s;
}

// ---------------------------------------------------------------------------
// CSR build step 3: scatter edge meta {src, ea0, ea1} into dst-grouped slots
// ---------------------------------------------------------------------------
__global__ __launch_bounds__(256) void scatter_edges(
    const int* __restrict__ ei, const float* __restrict__ ea,
    int* __restrict__ cursor, float4* __restrict__ meta, int E)
{
    int e = blockIdx.x * 256 + threadIdx.x;
    if (e >= E) return;
    int dst = ei[E + e];
    int pos = atomicAdd(&cursor[dst], 1);
    meta[pos] = make_float4(__int_as_float(ei[e]), ea[2 * e], ea[2 * e + 1], 0.f);
}

// ---------------------------------------------------------------------------
// Fused attention v3: one wave per dst node, FOUR edges in flight.
// Quarter (16 lanes) processes every 4th edge. Lane covers 8 channels as two
// float4 blocks: cA = ql*4 (head ql>>3), cB = 64+ql*4 (head 2+(ql>>3)) so each
// load instruction is a contiguous 256B chunk. Per-head QK reduce =
// shfl_xor 1,2,4 (inside the 8-lane head group; never crosses quarters).
// Each lane keeps two (m,s) states; quarters merge via shfl_xor 16 then 32.
// Sentinel m=-1e30 makes empty quarters / deg-0 exact (scale underflows to 0).
// ---------------------------------------------------------------------------
__global__ __launch_bounds__(256) void fused_attn(
    const float* __restrict__ q, const float* __restrict__ k,
    const float* __restrict__ v, const float* __restrict__ skip,
    const int* __restrict__ off, const float4* __restrict__ meta,
    const float* __restrict__ We, float* __restrict__ hout, int N)
{
    int wid = (int)((blockIdx.x * 256 + threadIdx.x) >> 6);  // dst node
    int lane = threadIdx.x & 63;
    if (wid >= N) return;
    int quarter = lane >> 4;         // 0..3: edge phase
    int ql = lane & 15;
    int cA = ql * 4;                 // block A channels, head ql>>3
    int cB = 64 + ql * 4;            // block B channels, head 2+(ql>>3)

    float4 w0A = *(const float4*)(We + cA);
    float4 w1A = *(const float4*)(We + HD + cA);
    float4 w0B = *(const float4*)(We + cB);
    float4 w1B = *(const float4*)(We + HD + cB);
    float4 qA = *(const float4*)(q + (size_t)wid * HD + cA);
    float4 qB = *(const float4*)(q + (size_t)wid * HD + cB);

    float mA = -1e30f, sA = 0.f, mB = -1e30f, sB = 0.f;
    float4 oA = make_float4(0.f, 0.f, 0.f, 0.f);
    float4 oB = make_float4(0.f, 0.f, 0.f, 0.f);

    int beg = off[wid], end = off[wid + 1];
    for (int j = beg + quarter; j < end; j += 4) {
        float4 md = meta[j];
        int src = __float_as_int(md.x);
        float4 eA, eB;
        eA.x = md.y * w0A.x + md.z * w1A.x;
        eA.y = md.y * w0A.y + md.z * w1A.y;
        eA.z = md.y * w0A.z + md.z * w1A.z;
        eA.w = md.y * w0A.w + md.z * w1A.w;
        eB.x = md.y * w0B.x + md.z * w1B.x;
        eB.y = md.y * w0B.y + md.z * w1B.y;
        eB.z = md.y * w0B.z + md.z * w1B.z;
        eB.w = md.y * w0B.w + md.z * w1B.w;
        float4 kA = *(const float4*)(k + (size_t)src * HD + cA);
        float4 kB = *(const float4*)(k + (size_t)src * HD + cB);
        float4 vA = *(const float4*)(v + (size_t)src * HD + cA);
        float4 vB = *(const float4*)(v + (size_t)src * HD + cB);
        float pA = qA.x * (kA.x + eA.x) + qA.y * (kA.y + eA.y)
                 + qA.z * (kA.z + eA.z) + qA.w * (kA.w + eA.w);
        float pB = qB.x * (kB.x + eB.x) + qB.y * (kB.y + eB.y)
                 + qB.z * (kB.z + eB.z) + qB.w * (kB.w + eB.w);
        pA += __shfl_xor(pA, 1); pA += __shfl_xor(pA, 2); pA += __shfl_xor(pA, 4);
        pB += __shfl_xor(pB, 1); pB += __shfl_xor(pB, 2); pB += __shfl_xor(pB, 4);
        pA *= 0.17677669529663687f;   // 1/sqrt(32)
        pB *= 0.17677669529663687f;
        float mnA = fmaxf(mA, pA);
        float scA = __expf(mA - mnA);
        float peA = __expf(pA - mnA);
        sA = sA * scA + peA;
        oA.x = oA.x * scA + peA * (vA.x + eA.x);
        oA.y = oA.y * scA + peA * (vA.y + eA.y);
        oA.z = oA.z * scA + peA * (vA.z + eA.z);
        oA.w = oA.w * scA + peA * (vA.w + eA.w);
        mA = mnA;
        float mnB = fmaxf(mB, pB);
        float scB = __expf(mB - mnB);
        float peB = __expf(pB - mnB);
        sB = sB * scB + peB;
        oB.x = oB.x * scB + peB * (vB.x + eB.x);
        oB.y = oB.y * scB + peB * (vB.y + eB.y);
        oB.z = oB.z * scB + peB * (vB.z + eB.z);
        oB.w = oB.w * scB + peB * (vB.w + eB.w);
        mB = mnB;
    }

    // ---- merge quarter states: xor 16, then xor 32 ----
#pragma unroll
    for (int d = 16; d <= 32; d <<= 1) {
        float moA = __shfl_xor(mA, d), soA = __shfl_xor(sA, d);
        float4 ooA;
        ooA.x = __shfl_xor(oA.x, d); ooA.y = __shfl_xor(oA.y, d);
        ooA.z = __shfl_xor(oA.z, d); ooA.w = __shfl_xor(oA.w, d);
        float mmA = fmaxf(mA, moA);
        float aA = __expf(mA - mmA), bA = __expf(moA - mmA);
        sA = sA * aA + soA * bA;
        oA.x = oA.x * aA + ooA.x * bA;
        oA.y = oA.y * aA + ooA.y * bA;
        oA.z = oA.z * aA + ooA.z * bA;
        oA.w = oA.w * aA + ooA.w * bA;
        mA = mmA;
        float moB = __shfl_xor(mB, d), soB = __shfl_xor(sB, d);
        float4 ooB;
        ooB.x = __shfl_xor(oB.x, d); ooB.y = __shfl_xor(oB.y, d);
        ooB.z = __shfl_xor(oB.z, d); ooB.w = __shfl_xor(oB.w, d);
        float mmB = fmaxf(mB, moB);
        float aB = __expf(mB - mmB), bB = __expf(moB - mmB);
        sB = sB * aB + soB * bB;
        oB.x = oB.x * aB + ooB.x * bB;
        oB.y = oB.y * aB + ooB.y * bB;
        oB.z = oB.z * aB + ooB.z * bB;
        oB.w = oB.w * aB + ooB.w * bB;
        mB = mmB;
    }

    if (quarter == 0) {
        float invA = 1.f / (sA + 1e-16f);    // deg==0: o=0 -> skip only
        float invB = 1.f / (sB + 1e-16f);
        float4 skA = *(const float4*)(skip + (size_t)wid * HD + cA);
        float4 skB = *(const float4*)(skip + (size_t)wid * HD + cB);
        float4 hvA, hvB;
        hvA.x = leaky(oA.x * invA + skA.x);
        hvA.y = leaky(oA.y * invA + skA.y);
        hvA.z = leaky(oA.z * invA + skA.z);
        hvA.w = leaky(oA.w * invA + skA.w);
        hvB.x = leaky(oB.x * invB + skB.x);
        hvB.y = leaky(oB.y * invB + skB.y);
        hvB.z = leaky(oB.z * invB + skB.z);
        hvB.w = leaky(oB.w * invB + skB.w);
        *(float4*)(hout + (size_t)wid * HD + cA) = hvA;
        *(float4*)(hout + (size_t)wid * HD + cB) = hvB;
    }
}

// ---------------------------------------------------------------------------
// emb = leaky(h @ W1 + b1)   (N x 128 @ 128 x 32)
// ---------------------------------------------------------------------------
__global__ __launch_bounds__(256) void emb_kernel(
    const float* __restrict__ h, const float* __restrict__ W1,
    const float* __restrict__ b1, float* __restrict__ emb, int N)
{
    int i = blockIdx.x * 256 + threadIdx.x;
    if (i >= N * CC) return;
    int row = i >> 5, col = i & 31;
    const float* hr = h + (size_t)row * HD;
    float acc = 0.f;
#pragma unroll 4
    for (int k = 0; k < HD; ++k) acc += hr[k] * W1[k * CC + col];
    emb[i] = leaky(acc + b1[col]);
}

// ---------------------------------------------------------------------------
// logits = emb @ W2 + b2; out = log_softmax(logits) per row (8 cols).
// ---------------------------------------------------------------------------
__global__ __launch_bounds__(256) void logits_kernel(
    const float* __restrict__ emb, const float* __restrict__ W2,
    const float* __restrict__ b2, float* __restrict__ out, int N)
{
    int i = blockIdx.x * 256 + threadIdx.x;
    int row = i >> 3, col = i & 7;
    if (row >= N) return;
    const float* er = emb + (size_t)row * CC;
    float acc = b2[col];
#pragma unroll
    for (int k = 0; k < CC; ++k) acc += er[k] * W2[k * 8 + col];
    float mx = acc;
    mx = fmaxf(mx, __shfl_xor(mx, 1));
    mx = fmaxf(mx, __shfl_xor(mx, 2));
    mx = fmaxf(mx, __shfl_xor(mx, 4));
    float ex = expf(acc - mx);
    float sm = ex;
    sm += __shfl_xor(sm, 1);
    sm += __shfl_xor(sm, 2);
    sm += __shfl_xor(sm, 4);
    out[i] = acc - mx - logf(sm);
}

extern "C" void kernel_launch(void* const* d_in, const int* in_sizes, int n_in,
                              void* d_out, int out_size, void* d_ws, size_t ws_size,
                              hipStream_t stream)
{
    const float* x  = (const float*)d_in[0];
    const int*   ei = (const int*)d_in[1];
    const float* ea = (const float*)d_in[2];
    const float* Wq = (const float*)d_in[3];
    const float* bq = (const float*)d_in[4];
    const float* Wk = (const float*)d_in[5];
    const float* bk = (const float*)d_in[6];
    const float* Wv = (const float*)d_in[7];
    const float* bv = (const float*)d_in[8];
    const float* We = (const float*)d_in[9];
    const float* Ws = (const float*)d_in[10];
    const float* bs = (const float*)d_in[11];
    const float* W1 = (const float*)d_in[12];
    const float* b1 = (const float*)d_in[13];
    const float* W2 = (const float*)d_in[14];
    const float* b2 = (const float*)d_in[15];

    int N = in_sizes[0] / HD;
    int E = in_sizes[1] / 2;

    float* ws = (float*)d_ws;
    size_t nd = (size_t)N * HD;
    float* hbuf = ws;
    float* qbuf = ws + nd;
    float* kbuf = ws + 2 * nd;
    float* vbuf = ws + 3 * nd;
    float* sbuf = ws + 4 * nd;
    float4* meta = (float4*)(ws + 5 * nd);           // E float4
    int* deg    = (int*)(ws + 5 * nd + 4 * (size_t)E);
    int* off    = deg + N;                            // N+1
    int* cursor = off + N + 1;                        // N
    size_t frag_byte = (((5 * nd + 4 * (size_t)E) + (size_t)(3 * N + 1)) * 4 + 15)
                       & ~(size_t)15;
    ushort* Wfrag = (ushort*)((char*)d_ws + frag_byte);

    int gemm_gx = (N + 63) / 64;
    int edge_gx = (E + 255) / 256;
    int attn_gx = (N + 3) / 4;

    // ---- CSR build + weight fragment conversion (once per call) ----
    hipMemsetAsync(deg, 0, (size_t)N * sizeof(int), stream);
    count_deg<<<edge_gx, 256, 0, stream>>>(ei, deg, E);
    scan_kernel<<<1, 1024, 0, stream>>>(deg, off, cursor, N);
    scatter_edges<<<edge_gx, 256, 0, stream>>>(ei, ea, cursor, meta, E);
    conv_w<<<(12 * 8 * 4 * 64 + 255) / 256, 256, 0, stream>>>(Wq, Wk, Wv, Ws, Wfrag);

    for (int l = 0; l < 3; ++l) {
        const float* cur = (l == 0) ? x : hbuf;
        const float* Wel = We + (size_t)l * 2 * HD;

        gemm4_mfma<<<dim3(gemm_gx, 2), 512, 0, stream>>>(
            cur, Wfrag,
            bq + (size_t)l * HD, bk + (size_t)l * HD,
            bv + (size_t)l * HD, bs + (size_t)l * HD,
            qbuf, kbuf, vbuf, sbuf, l, N);

        fused_attn<<<attn_gx, 256, 0, stream>>>(
            qbuf, kbuf, vbuf, sbuf, off, meta, Wel, hbuf, N);
    }

    // head: emb = leaky(h@W1+b1) -> reuse kbuf; logits+log_softmax -> d_out
    emb_kernel<<<(N * CC + 255) / 256, 256, 0, stream>>>(hbuf, W1, b1, kbuf, N);
    logits_kernel<<<(N * 8 + 255) / 256, 256, 0, stream>>>(kbuf, W2, b2, (float*)d_out, N);
}

// Round 13
// 562.434 us; speedup vs baseline: 1.0380x; 1.0380x over previous
//
#include <hip/hip_runtime.h>
#include <hip/hip_bf16.h>
#include <math.h>

#define HD 128   // hidden dim = H*C
#define NH 4     // heads
#define CC 32    // channels per head

typedef __attribute__((ext_vector_type(8))) short short8;
typedef __attribute__((ext_vector_type(4))) float f32x4;

__device__ __forceinline__ float leaky(float x) { return x > 0.f ? x : 0.01f * x; }

// f32 -> bf16 round-to-nearest-even (finite values)
__device__ __forceinline__ ushort bf16_rne(float f) {
    unsigned u = __float_as_uint(f);
    return (ushort)((u + 0x7fffu + ((u >> 16) & 1u)) >> 16);
}
__device__ __forceinline__ float bf16_f(ushort h) {
    return __uint_as_float(((unsigned)h) << 16);
}

// Wfrag layout: [mg(12)][ct(8)][kk(4)][lane(64)][j(8)] ushort, hi half then lo
// half at +WFRAG_HALF. mg = layer*4 + mat. B-frag mapping (16x16x32):
// col = ct*16+(lane&15), k = kk*32+(lane>>4)*8+j.   (verified: r5/r7/r8 passed)
#define WFRAG_HALF (12 * 32 * 64 * 8)

// ---------------------------------------------------------------------------
// Convert W (f32, [3][128][128] x 4 matrices) into bf16 hi/lo B-fragments.
// ---------------------------------------------------------------------------
__global__ __launch_bounds__(256) void conv_w(
    const float* __restrict__ Wq, const float* __restrict__ Wk,
    const float* __restrict__ Wv, const float* __restrict__ Wsk,
    ushort* __restrict__ frag)
{
    int tid = blockIdx.x * 256 + threadIdx.x;
    if (tid >= 12 * 8 * 4 * 64) return;
    int lane = tid & 63;
    int kk = (tid >> 6) & 3;
    int ct = (tid >> 8) & 7;
    int mg = tid >> 11;            // 0..11
    int l = mg >> 2, m = mg & 3;
    const float* src = ((m == 0) ? Wq : (m == 1) ? Wk : (m == 2) ? Wv : Wsk)
                       + (size_t)l * HD * HD;
    int col = ct * 16 + (lane & 15);
    int k0 = kk * 32 + (lane >> 4) * 8;
    ushort* dst = frag + (size_t)tid * 8;
#pragma unroll
    for (int j = 0; j < 8; ++j) {
        float w = src[(size_t)(k0 + j) * HD + col];
        ushort h = bf16_rne(w);
        dst[j] = h;
        dst[WFRAG_HALF + j] = bf16_rne(w - bf16_f(h));
    }
}

// ---------------------------------------------------------------------------
// MFMA GEMM, split-bf16 (hh+hl+lh). 512 threads = 8 waves.
// Block = 64 rows. Wave = (p, h): p in 0..3 owns cols p*32..p*32+31, h in 0..1
// owns rows h*32..h*32+31. W-frags register-resident. Epilogue bounces acc
// through wave-private LDS so stores are full aligned 128B lines (r8 fix).
// ---------------------------------------------------------------------------
__global__ __launch_bounds__(512) void gemm4_mfma(
    const float* __restrict__ X, const ushort* __restrict__ Wfrag,
    const float* __restrict__ bq, const float* __restrict__ bk,
    const float* __restrict__ bv, const float* __restrict__ bsk,
    float* __restrict__ Oq, float* __restrict__ Ok,
    float* __restrict__ Ov, float* __restrict__ Osk,
    int layer, int N)
{
    __shared__ __align__(16) ushort Xh[64 * HD];   // 16 KB
    __shared__ __align__(16) ushort Xl[64 * HD];   // 16 KB
    __shared__ __align__(16) float  Ot[8][16 * 36]; // 18 KB wave-private scratch

    int t = threadIdx.x;
    int row0 = blockIdx.x * 64;

    // ---- stage X tile as hi/lo bf16, swizzled: byte ^= (row&7)<<4 ----
#pragma unroll
    for (int i = 0; i < 4; ++i) {
        int idx = t + i * 512;           // 0..2047
        int r = idx >> 5;                // 0..63
        int c4 = (idx & 31) * 4;         // first k of this float4
        int gr = row0 + r;
        float4 xv = (gr < N) ? *(const float4*)(X + (size_t)gr * HD + c4)
                             : make_float4(0.f, 0.f, 0.f, 0.f);
        ushort h0 = bf16_rne(xv.x), h1 = bf16_rne(xv.y),
               h2 = bf16_rne(xv.z), h3 = bf16_rne(xv.w);
        ushort l0 = bf16_rne(xv.x - bf16_f(h0)), l1 = bf16_rne(xv.y - bf16_f(h1)),
               l2 = bf16_rne(xv.z - bf16_f(h2)), l3 = bf16_rne(xv.w - bf16_f(h3));
        int off = r * 256 + c4 * 2;                 // byte offset, 8B-aligned
        int swz = off ^ ((r & 7) << 4);
        *(ushort4*)((char*)Xh + swz) = make_ushort4(h0, h1, h2, h3);
        *(ushort4*)((char*)Xl + swz) = make_ushort4(l0, l1, l2, l3);
    }
    __syncthreads();

    int w = t >> 6;                  // wave id
    int p = w & 3;                   // col pair: cols p*32..p*32+31
    int h = w >> 2;                  // row half: rows h*32..h*32+31
    int lane = t & 63;
    int col16 = lane & 15;
    int quad = lane >> 4;
    float* scratch = Ot[w];

#pragma unroll
    for (int mm = 0; mm < 2; ++mm) {
        int mat = blockIdx.y * 2 + mm;
        const float* b = (mat == 0) ? bq : (mat == 1) ? bk : (mat == 2) ? bv : bsk;
        float* O = (mat == 0) ? Oq : (mat == 1) ? Ok : (mat == 2) ? Ov : Osk;
        int mg = layer * 4 + mat;

        // ---- load this wave's 2 col-tiles' W fragments into registers ----
        short8 bh[2][4], bl[2][4];
#pragma unroll
        for (int cl = 0; cl < 2; ++cl) {
            int ct = p * 2 + cl;
#pragma unroll
            for (int kk = 0; kk < 4; ++kk) {
                const ushort* wp = Wfrag + ((size_t)((mg * 8 + ct) * 4 + kk) * 64 + lane) * 8;
                bh[cl][kk] = *(const short8*)wp;
                bl[cl][kk] = *(const short8*)(wp + WFRAG_HALF);
            }
        }
        float bcol0 = b[(p * 2 + 0) * 16 + col16];
        float bcol1 = b[(p * 2 + 1) * 16 + col16];

#pragma unroll
        for (int mtl = 0; mtl < 2; ++mtl) {
            int arow = h * 32 + mtl * 16 + col16;    // A row for this lane
            int abase = arow * 256;
            int aswz = (arow & 7) << 4;
            f32x4 c0a = {0.f,0.f,0.f,0.f}, c0b = {0.f,0.f,0.f,0.f}, c0c = {0.f,0.f,0.f,0.f};
            f32x4 c1a = {0.f,0.f,0.f,0.f}, c1b = {0.f,0.f,0.f,0.f}, c1c = {0.f,0.f,0.f,0.f};
#pragma unroll
            for (int kk = 0; kk < 4; ++kk) {
                int koff = abase + kk * 64 + quad * 16;   // bytes
                short8 ah = *(const short8*)((const char*)Xh + (koff ^ aswz));
                short8 al = *(const short8*)((const char*)Xl + (koff ^ aswz));
                c0a = __builtin_amdgcn_mfma_f32_16x16x32_bf16(ah, bh[0][kk], c0a, 0, 0, 0);
                c0b = __builtin_amdgcn_mfma_f32_16x16x32_bf16(ah, bl[0][kk], c0b, 0, 0, 0);
                c0c = __builtin_amdgcn_mfma_f32_16x16x32_bf16(al, bh[0][kk], c0c, 0, 0, 0);
                c1a = __builtin_amdgcn_mfma_f32_16x16x32_bf16(ah, bh[1][kk], c1a, 0, 0, 0);
                c1b = __builtin_amdgcn_mfma_f32_16x16x32_bf16(ah, bl[1][kk], c1b, 0, 0, 0);
                c1c = __builtin_amdgcn_mfma_f32_16x16x32_bf16(al, bh[1][kk], c1c, 0, 0, 0);
            }
            // ---- epilogue via wave-private LDS -> full-line stores ----
#pragma unroll
            for (int i = 0; i < 4; ++i) {
                int rr = quad * 4 + i;
                scratch[rr * 36 + col16]      = c0a[i] + c0b[i] + c0c[i] + bcol0;
                scratch[rr * 36 + 16 + col16] = c1a[i] + c1b[i] + c1c[i] + bcol1;
            }
#pragma unroll
            for (int s = 0; s < 2; ++s) {
                int row = s * 8 + (lane >> 3);
                int c4 = (lane & 7) * 4;
                float4 v = *(const float4*)(&scratch[row * 36 + c4]);
                int gr = row0 + h * 32 + mtl * 16 + row;
                if (gr < N)
                    *(float4*)(O + (size_t)gr * HD + p * 32 + c4) = v;
            }
        }
    }
}

// ---------------------------------------------------------------------------
// Pack k,v (f32) into interleaved bf16: kv[node] = [128 k-bf16 | 128 v-bf16]
// (512 B per node). Fully coalesced reads and writes.
// ---------------------------------------------------------------------------
__global__ __launch_bounds__(256) void pack_kv(
    const float* __restrict__ k, const float* __restrict__ v,
    ushort* __restrict__ kv, int N)
{
    int i = blockIdx.x * 256 + threadIdx.x;   // over N*32
    if (i >= N * 32) return;
    int node = i >> 5, g = i & 31;
    float4 kf = *(const float4*)(k + (size_t)node * HD + g * 4);
    float4 vf = *(const float4*)(v + (size_t)node * HD + g * 4);
    ushort4 ku = make_ushort4(bf16_rne(kf.x), bf16_rne(kf.y), bf16_rne(kf.z), bf16_rne(kf.w));
    ushort4 vu = make_ushort4(bf16_rne(vf.x), bf16_rne(vf.y), bf16_rne(vf.z), bf16_rne(vf.w));
    *(ushort4*)(kv + (size_t)node * 256 + g * 4) = ku;
    *(ushort4*)(kv + (size_t)node * 256 + 128 + g * 4) = vu;
}

// ---------------------------------------------------------------------------
// CSR build step 1: deg[dst]++ per edge
// ---------------------------------------------------------------------------
__global__ __launch_bounds__(256) void count_deg(
    const int* __restrict__ ei, int* __restrict__ deg, int E)
{
    int e = blockIdx.x * 256 + threadIdx.x;
    if (e < E) atomicAdd(&deg[ei[E + e]], 1);
}

// ---------------------------------------------------------------------------
// CSR build step 2: exclusive scan of deg -> off (N+1), duplicate into cursor.
// ---------------------------------------------------------------------------
__global__ __launch_bounds__(1024) void scan_kernel(
    const int* __restrict__ deg, int* __restrict__ off,
    int* __restrict__ cursor, int N)
{
    __shared__ int wsum[16];
    __shared__ int carry_s;
    int tid = threadIdx.x;
    int lane = tid & 63;
    int w = tid >> 6;
    if (tid == 0) carry_s = 0;
    __syncthreads();
    for (int base = 0; base < N; base += 1024) {
        int idx = base + tid;
        int x = (idx < N) ? deg[idx] : 0;
        int val = x;
#pragma unroll
        for (int s = 1; s < 64; s <<= 1) {
            int t = __shfl_up(val, s);
            if (lane >= s) val += t;
        }
        if (lane == 63) wsum[w] = val;
        __syncthreads();
        if (w == 0) {
            int t = (lane < 16) ? wsum[lane] : 0;
#pragma unroll
            for (int s = 1; s < 16; s <<= 1) {
                int u = __shfl_up(t, s);
                if (lane >= s) t += u;
            }
            if (lane < 16) wsum[lane] = t;  // inclusive wave totals
        }
        __syncthreads();
        int carry = carry_s;
        int wexcl = (w > 0) ? wsum[w - 1] : 0;
        int excl = carry + wexcl + (val - x);
        if (idx < N) { off[idx] = excl; cursor[idx] = excl; }
        __syncthreads();
        if (tid == 0) carry_s = carry + wsum[15];
        __syncthreads();
    }
    if (threadIdx.x == 0) off[N] = carry_s;
}

// ---------------------------------------------------------------------------
// CSR build step 3: scatter edge meta {src, ea0, ea1} into dst-grouped slots
// ---------------------------------------------------------------------------
__global__ __launch_bounds__(256) void scatter_edges(
    const int* __restrict__ ei, const float* __restrict__ ea,
    int* __restrict__ cursor, float4* __restrict__ meta, int E)
{
    int e = blockIdx.x * 256 + threadIdx.x;
    if (e >= E) return;
    int dst = ei[E + e];
    int pos = atomicAdd(&cursor[dst], 1);
    meta[pos] = make_float4(__int_as_float(ei[e]), ea[2 * e], ea[2 * e + 1], 0.f);
}

// ---------------------------------------------------------------------------
// Fused attention v4: one wave per dst node, 4 edges in flight, bf16 kv.
// Quarter (16 lanes) processes every 4th edge; lane ql covers 8 contiguous
// channels c8 = ql*8 (head = ql>>2, 4 lanes per head). Per edge: ONE 16B
// bf16 k-load + ONE 16B bf16 v-load per lane (16 lanes = 256B each; 4 lines
// per edge vs 8 for f32). QK reduce = shfl_xor 1,2 (4-lane head group).
// e-bias, q, softmax state all f32. Quarters merge via shfl_xor 16, 32.
// Sentinel m=-1e30 keeps empty quarters / deg-0 exact.
// ---------------------------------------------------------------------------
__global__ __launch_bounds__(256) void fused_attn(
    const float* __restrict__ q, const ushort* __restrict__ kv,
    const float* __restrict__ skip,
    const int* __restrict__ off, const float4* __restrict__ meta,
    const float* __restrict__ We, float* __restrict__ hout, int N)
{
    int wid = (int)((blockIdx.x * 256 + threadIdx.x) >> 6);  // dst node
    int lane = threadIdx.x & 63;
    if (wid >= N) return;
    int quarter = lane >> 4;         // 0..3: edge phase
    int ql = lane & 15;
    int c8 = ql * 8;                 // 8 channels, head = ql>>2

    float4 w0a = *(const float4*)(We + c8);
    float4 w0b = *(const float4*)(We + c8 + 4);
    float4 w1a = *(const float4*)(We + HD + c8);
    float4 w1b = *(const float4*)(We + HD + c8 + 4);
    float4 qa = *(const float4*)(q + (size_t)wid * HD + c8);
    float4 qb = *(const float4*)(q + (size_t)wid * HD + c8 + 4);

    float m = -1e30f, s = 0.f;
    float o[8];
#pragma unroll
    for (int i = 0; i < 8; ++i) o[i] = 0.f;

    int beg = off[wid], end = off[wid + 1];
    for (int j = beg + quarter; j < end; j += 4) {
        float4 md = meta[j];
        int src = __float_as_int(md.x);
        float e[8];
        e[0] = md.y * w0a.x + md.z * w1a.x;
        e[1] = md.y * w0a.y + md.z * w1a.y;
        e[2] = md.y * w0a.z + md.z * w1a.z;
        e[3] = md.y * w0a.w + md.z * w1a.w;
        e[4] = md.y * w0b.x + md.z * w1b.x;
        e[5] = md.y * w0b.y + md.z * w1b.y;
        e[6] = md.y * w0b.z + md.z * w1b.z;
        e[7] = md.y * w0b.w + md.z * w1b.w;
        short8 ku = *(const short8*)(kv + (size_t)src * 256 + c8);
        short8 vu = *(const short8*)(kv + (size_t)src * 256 + 128 + c8);
        float kf[8], vf[8];
#pragma unroll
        for (int i = 0; i < 8; ++i) {
            kf[i] = __uint_as_float(((unsigned)(ushort)ku[i]) << 16);
            vf[i] = __uint_as_float(((unsigned)(ushort)vu[i]) << 16);
        }
        float p = qa.x * (kf[0] + e[0]) + qa.y * (kf[1] + e[1])
                + qa.z * (kf[2] + e[2]) + qa.w * (kf[3] + e[3])
                + qb.x * (kf[4] + e[4]) + qb.y * (kf[5] + e[5])
                + qb.z * (kf[6] + e[6]) + qb.w * (kf[7] + e[7]);
        p += __shfl_xor(p, 1);
        p += __shfl_xor(p, 2);       // 4-lane head group reduce
        p *= 0.17677669529663687f;   // 1/sqrt(32)
        float mn = fmaxf(m, p);
        float sc = __expf(m - mn);
        float pe = __expf(p - mn);
        s = s * sc + pe;
#pragma unroll
        for (int i = 0; i < 8; ++i) o[i] = o[i] * sc + pe * (vf[i] + e[i]);
        m = mn;
    }

    // ---- merge quarter states: xor 16, then xor 32 ----
#pragma unroll
    for (int d = 16; d <= 32; d <<= 1) {
        float mo = __shfl_xor(m, d), so = __shfl_xor(s, d);
        float oo[8];
#pragma unroll
        for (int i = 0; i < 8; ++i) oo[i] = __shfl_xor(o[i], d);
        float mm = fmaxf(m, mo);
        float a = __expf(m - mm), b = __expf(mo - mm);
        s = s * a + so * b;
#pragma unroll
        for (int i = 0; i < 8; ++i) o[i] = o[i] * a + oo[i] * b;
        m = mm;
    }

    if (quarter == 0) {
        float inv = 1.f / (s + 1e-16f);      // deg==0: o=0 -> skip only
        float4 ska = *(const float4*)(skip + (size_t)wid * HD + c8);
        float4 skb = *(const float4*)(skip + (size_t)wid * HD + c8 + 4);
        float4 ha, hb;
        ha.x = leaky(o[0] * inv + ska.x);
        ha.y = leaky(o[1] * inv + ska.y);
        ha.z = leaky(o[2] * inv + ska.z);
        ha.w = leaky(o[3] * inv + ska.w);
        hb.x = leaky(o[4] * inv + skb.x);
        hb.y = leaky(o[5] * inv + skb.y);
        hb.z = leaky(o[6] * inv + skb.z);
        hb.w = leaky(o[7] * inv + skb.w);
        *(float4*)(hout + (size_t)wid * HD + c8) = ha;
        *(float4*)(hout + (size_t)wid * HD + c8 + 4) = hb;
    }
}

// ---------------------------------------------------------------------------
// emb = leaky(h @ W1 + b1)   (N x 128 @ 128 x 32)
// ---------------------------------------------------------------------------
__global__ __launch_bounds__(256) void emb_kernel(
    const float* __restrict__ h, const float* __restrict__ W1,
    const float* __restrict__ b1, float* __restrict__ emb, int N)
{
    int i = blockIdx.x * 256 + threadIdx.x;
    if (i >= N * CC) return;
    int row = i >> 5, col = i & 31;
    const float* hr = h + (size_t)row * HD;
    float acc = 0.f;
#pragma unroll 4
    for (int k = 0; k < HD; ++k) acc += hr[k] * W1[k * CC + col];
    emb[i] = leaky(acc + b1[col]);
}

// ---------------------------------------------------------------------------
// logits = emb @ W2 + b2; out = log_softmax(logits) per row (8 cols).
// ---------------------------------------------------------------------------
__global__ __launch_bounds__(256) void logits_kernel(
    const float* __restrict__ emb, const float* __restrict__ W2,
    const float* __restrict__ b2, float* __restrict__ out, int N)
{
    int i = blockIdx.x * 256 + threadIdx.x;
    int row = i >> 3, col = i & 7;
    if (row >= N) return;
    const float* er = emb + (size_t)row * CC;
    float acc = b2[col];
#pragma unroll
    for (int k = 0; k < CC; ++k) acc += er[k] * W2[k * 8 + col];
    float mx = acc;
    mx = fmaxf(mx, __shfl_xor(mx, 1));
    mx = fmaxf(mx, __shfl_xor(mx, 2));
    mx = fmaxf(mx, __shfl_xor(mx, 4));
    float ex = expf(acc - mx);
    float sm = ex;
    sm += __shfl_xor(sm, 1);
    sm += __shfl_xor(sm, 2);
    sm += __shfl_xor(sm, 4);
    out[i] = acc - mx - logf(sm);
}

extern "C" void kernel_launch(void* const* d_in, const int* in_sizes, int n_in,
                              void* d_out, int out_size, void* d_ws, size_t ws_size,
                              hipStream_t stream)
{
    const float* x  = (const float*)d_in[0];
    const int*   ei = (const int*)d_in[1];
    const float* ea = (const float*)d_in[2];
    const float* Wq = (const float*)d_in[3];
    const float* bq = (const float*)d_in[4];
    const float* Wk = (const float*)d_in[5];
    const float* bk = (const float*)d_in[6];
    const float* Wv = (const float*)d_in[7];
    const float* bv = (const float*)d_in[8];
    const float* We = (const float*)d_in[9];
    const float* Ws = (const float*)d_in[10];
    const float* bs = (const float*)d_in[11];
    const float* W1 = (const float*)d_in[12];
    const float* b1 = (const float*)d_in[13];
    const float* W2 = (const float*)d_in[14];
    const float* b2 = (const float*)d_in[15];

    int N = in_sizes[0] / HD;
    int E = in_sizes[1] / 2;

    float* ws = (float*)d_ws;
    size_t nd = (size_t)N * HD;
    float* hbuf = ws;
    float* qbuf = ws + nd;
    float* kbuf = ws + 2 * nd;
    float* vbuf = ws + 3 * nd;
    float* sbuf = ws + 4 * nd;
    float4* meta = (float4*)(ws + 5 * nd);           // E float4
    int* deg    = (int*)(ws + 5 * nd + 4 * (size_t)E);
    int* off    = deg + N;                            // N+1
    int* cursor = off + N + 1;                        // N
    size_t frag_byte = (((5 * nd + 4 * (size_t)E) + (size_t)(3 * N + 1)) * 4 + 15)
                       & ~(size_t)15;
    ushort* Wfrag = (ushort*)((char*)d_ws + frag_byte);
    ushort* kvbuf = Wfrag + 2 * (size_t)WFRAG_HALF;   // N*256 ushorts (bf16 kv)

    int gemm_gx = (N + 63) / 64;
    int edge_gx = (E + 255) / 256;
    int attn_gx = (N + 3) / 4;

    // ---- CSR build + weight fragment conversion (once per call) ----
    hipMemsetAsync(deg, 0, (size_t)N * sizeof(int), stream);
    count_deg<<<edge_gx, 256, 0, stream>>>(ei, deg, E);
    scan_kernel<<<1, 1024, 0, stream>>>(deg, off, cursor, N);
    scatter_edges<<<edge_gx, 256, 0, stream>>>(ei, ea, cursor, meta, E);
    conv_w<<<(12 * 8 * 4 * 64 + 255) / 256, 256, 0, stream>>>(Wq, Wk, Wv, Ws, Wfrag);

    for (int l = 0; l < 3; ++l) {
        const float* cur = (l == 0) ? x : hbuf;
        const float* Wel = We + (size_t)l * 2 * HD;

        gemm4_mfma<<<dim3(gemm_gx, 2), 512, 0, stream>>>(
            cur, Wfrag,
            bq + (size_t)l * HD, bk + (size_t)l * HD,
            bv + (size_t)l * HD, bs + (size_t)l * HD,
            qbuf, kbuf, vbuf, sbuf, l, N);

        pack_kv<<<(N * 32 + 255) / 256, 256, 0, stream>>>(kbuf, vbuf, kvbuf, N);

        fused_attn<<<attn_gx, 256, 0, stream>>>(
            qbuf, kvbuf, sbuf, off, meta, Wel, hbuf, N);
    }

    // head: emb = leaky(h@W1+b1) -> reuse kbuf; logits+log_softmax -> d_out
    emb_kernel<<<(N * CC + 255) / 256, 256, 0, stream>>>(hbuf, W1, b1, kbuf, N);
    logits_kernel<<<(N * 8 + 255) / 256, 256, 0, stream>>>(kbuf, W2, b2, (float*)d_out, N);
}

// Round 14
// 524.319 us; speedup vs baseline: 1.1135x; 1.0727x over previous
//
#include <hip/hip_runtime.h>
#include <hip/hip_bf16.h>
#include <math.h>

#define HD 128   // hidden dim = H*C
#define NH 4     // heads
#define CC 32    // channels per head

typedef __attribute__((ext_vector_type(8))) short short8;
typedef __attribute__((ext_vector_type(4))) float f32x4;

__device__ __forceinline__ float leaky(float x) { return x > 0.f ? x : 0.01f * x; }

// f32 -> bf16 round-to-nearest-even (finite values)
__device__ __forceinline__ ushort bf16_rne(float f) {
    unsigned u = __float_as_uint(f);
    return (ushort)((u + 0x7fffu + ((u >> 16) & 1u)) >> 16);
}
__device__ __forceinline__ float bf16_f(ushort h) {
    return __uint_as_float(((unsigned)h) << 16);
}

// Wfrag layout: [mg(12)][ct(8)][kk(4)][lane(64)][j(8)] ushort, hi half then lo
// half at +WFRAG_HALF. mg = layer*4 + mat. B-frag mapping (16x16x32):
// col = ct*16+(lane&15), k = kk*32+(lane>>4)*8+j.   (verified: r5/r7/r8 passed)
#define WFRAG_HALF (12 * 32 * 64 * 8)

// ---------------------------------------------------------------------------
// Convert W (f32, [3][128][128] x 4 matrices) into bf16 hi/lo B-fragments.
// ---------------------------------------------------------------------------
__global__ __launch_bounds__(256) void conv_w(
    const float* __restrict__ Wq, const float* __restrict__ Wk,
    const float* __restrict__ Wv, const float* __restrict__ Wsk,
    ushort* __restrict__ frag)
{
    int tid = blockIdx.x * 256 + threadIdx.x;
    if (tid >= 12 * 8 * 4 * 64) return;
    int lane = tid & 63;
    int kk = (tid >> 6) & 3;
    int ct = (tid >> 8) & 7;
    int mg = tid >> 11;            // 0..11
    int l = mg >> 2, m = mg & 3;
    const float* src = ((m == 0) ? Wq : (m == 1) ? Wk : (m == 2) ? Wv : Wsk)
                       + (size_t)l * HD * HD;
    int col = ct * 16 + (lane & 15);
    int k0 = kk * 32 + (lane >> 4) * 8;
    ushort* dst = frag + (size_t)tid * 8;
#pragma unroll
    for (int j = 0; j < 8; ++j) {
        float w = src[(size_t)(k0 + j) * HD + col];
        ushort h = bf16_rne(w);
        dst[j] = h;
        dst[WFRAG_HALF + j] = bf16_rne(w - bf16_f(h));
    }
}

// ---------------------------------------------------------------------------
// MFMA GEMM, split-bf16 (hh+hl+lh). 512 threads = 8 waves.
// Block = 64 rows. Wave = (p, h): p in 0..3 owns cols p*32..p*32+31, h in 0..1
// owns rows h*32..h*32+31. W-frags register-resident. Epilogue bounces acc
// through wave-private LDS so stores are full aligned 128B lines (r8 fix).
// ---------------------------------------------------------------------------
__global__ __launch_bounds__(512) void gemm4_mfma(
    const float* __restrict__ X, const ushort* __restrict__ Wfrag,
    const float* __restrict__ bq, const float* __restrict__ bk,
    const float* __restrict__ bv, const float* __restrict__ bsk,
    float* __restrict__ Oq, float* __restrict__ Ok,
    float* __restrict__ Ov, float* __restrict__ Osk,
    int layer, int N)
{
    __shared__ __align__(16) ushort Xh[64 * HD];   // 16 KB
    __shared__ __align__(16) ushort Xl[64 * HD];   // 16 KB
    __shared__ __align__(16) float  Ot[8][16 * 36]; // 18 KB wave-private scratch

    int t = threadIdx.x;
    int row0 = blockIdx.x * 64;

    // ---- stage X tile as hi/lo bf16, swizzled: byte ^= (row&7)<<4 ----
#pragma unroll
    for (int i = 0; i < 4; ++i) {
        int idx = t + i * 512;           // 0..2047
        int r = idx >> 5;                // 0..63
        int c4 = (idx & 31) * 4;         // first k of this float4
        int gr = row0 + r;
        float4 xv = (gr < N) ? *(const float4*)(X + (size_t)gr * HD + c4)
                             : make_float4(0.f, 0.f, 0.f, 0.f);
        ushort h0 = bf16_rne(xv.x), h1 = bf16_rne(xv.y),
               h2 = bf16_rne(xv.z), h3 = bf16_rne(xv.w);
        ushort l0 = bf16_rne(xv.x - bf16_f(h0)), l1 = bf16_rne(xv.y - bf16_f(h1)),
               l2 = bf16_rne(xv.z - bf16_f(h2)), l3 = bf16_rne(xv.w - bf16_f(h3));
        int off = r * 256 + c4 * 2;                 // byte offset, 8B-aligned
        int swz = off ^ ((r & 7) << 4);
        *(ushort4*)((char*)Xh + swz) = make_ushort4(h0, h1, h2, h3);
        *(ushort4*)((char*)Xl + swz) = make_ushort4(l0, l1, l2, l3);
    }
    __syncthreads();

    int w = t >> 6;                  // wave id
    int p = w & 3;                   // col pair: cols p*32..p*32+31
    int h = w >> 2;                  // row half: rows h*32..h*32+31
    int lane = t & 63;
    int col16 = lane & 15;
    int quad = lane >> 4;
    float* scratch = Ot[w];

#pragma unroll
    for (int mm = 0; mm < 2; ++mm) {
        int mat = blockIdx.y * 2 + mm;
        const float* b = (mat == 0) ? bq : (mat == 1) ? bk : (mat == 2) ? bv : bsk;
        float* O = (mat == 0) ? Oq : (mat == 1) ? Ok : (mat == 2) ? Ov : Osk;
        int mg = layer * 4 + mat;

        // ---- load this wave's 2 col-tiles' W fragments into registers ----
        short8 bh[2][4], bl[2][4];
#pragma unroll
        for (int cl = 0; cl < 2; ++cl) {
            int ct = p * 2 + cl;
#pragma unroll
            for (int kk = 0; kk < 4; ++kk) {
                const ushort* wp = Wfrag + ((size_t)((mg * 8 + ct) * 4 + kk) * 64 + lane) * 8;
                bh[cl][kk] = *(const short8*)wp;
                bl[cl][kk] = *(const short8*)(wp + WFRAG_HALF);
            }
        }
        float bcol0 = b[(p * 2 + 0) * 16 + col16];
        float bcol1 = b[(p * 2 + 1) * 16 + col16];

#pragma unroll
        for (int mtl = 0; mtl < 2; ++mtl) {
            int arow = h * 32 + mtl * 16 + col16;    // A row for this lane
            int abase = arow * 256;
            int aswz = (arow & 7) << 4;
            f32x4 c0a = {0.f,0.f,0.f,0.f}, c0b = {0.f,0.f,0.f,0.f}, c0c = {0.f,0.f,0.f,0.f};
            f32x4 c1a = {0.f,0.f,0.f,0.f}, c1b = {0.f,0.f,0.f,0.f}, c1c = {0.f,0.f,0.f,0.f};
#pragma unroll
            for (int kk = 0; kk < 4; ++kk) {
                int koff = abase + kk * 64 + quad * 16;   // bytes
                short8 ah = *(const short8*)((const char*)Xh + (koff ^ aswz));
                short8 al = *(const short8*)((const char*)Xl + (koff ^ aswz));
                c0a = __builtin_amdgcn_mfma_f32_16x16x32_bf16(ah, bh[0][kk], c0a, 0, 0, 0);
                c0b = __builtin_amdgcn_mfma_f32_16x16x32_bf16(ah, bl[0][kk], c0b, 0, 0, 0);
                c0c = __builtin_amdgcn_mfma_f32_16x16x32_bf16(al, bh[0][kk], c0c, 0, 0, 0);
                c1a = __builtin_amdgcn_mfma_f32_16x16x32_bf16(ah, bh[1][kk], c1a, 0, 0, 0);
                c1b = __builtin_amdgcn_mfma_f32_16x16x32_bf16(ah, bl[1][kk], c1b, 0, 0, 0);
                c1c = __builtin_amdgcn_mfma_f32_16x16x32_bf16(al, bh[1][kk], c1c, 0, 0, 0);
            }
            // ---- epilogue via wave-private LDS -> full-line stores ----
#pragma unroll
            for (int i = 0; i < 4; ++i) {
                int rr = quad * 4 + i;
                scratch[rr * 36 + col16]      = c0a[i] + c0b[i] + c0c[i] + bcol0;
                scratch[rr * 36 + 16 + col16] = c1a[i] + c1b[i] + c1c[i] + bcol1;
            }
#pragma unroll
            for (int s = 0; s < 2; ++s) {
                int row = s * 8 + (lane >> 3);
                int c4 = (lane & 7) * 4;
                float4 v = *(const float4*)(&scratch[row * 36 + c4]);
                int gr = row0 + h * 32 + mtl * 16 + row;
                if (gr < N)
                    *(float4*)(O + (size_t)gr * HD + p * 32 + c4) = v;
            }
        }
    }
}

// ---------------------------------------------------------------------------
// Pack k,v (f32) into interleaved bf16: kv[node] = [128 k-bf16 | 128 v-bf16]
// (512 B per node). Fully coalesced reads and writes.
// ---------------------------------------------------------------------------
__global__ __launch_bounds__(256) void pack_kv(
    const float* __restrict__ k, const float* __restrict__ v,
    ushort* __restrict__ kv, int N)
{
    int i = blockIdx.x * 256 + threadIdx.x;   // over N*32
    if (i >= N * 32) return;
    int node = i >> 5, g = i & 31;
    float4 kf = *(const float4*)(k + (size_t)node * HD + g * 4);
    float4 vf = *(const float4*)(v + (size_t)node * HD + g * 4);
    ushort4 ku = make_ushort4(bf16_rne(kf.x), bf16_rne(kf.y), bf16_rne(kf.z), bf16_rne(kf.w));
    ushort4 vu = make_ushort4(bf16_rne(vf.x), bf16_rne(vf.y), bf16_rne(vf.z), bf16_rne(vf.w));
    *(ushort4*)(kv + (size_t)node * 256 + g * 4) = ku;
    *(ushort4*)(kv + (size_t)node * 256 + 128 + g * 4) = vu;
}

// ---------------------------------------------------------------------------
// CSR build step 1: deg[dst]++ per edge
// ---------------------------------------------------------------------------
__global__ __launch_bounds__(256) void count_deg(
    const int* __restrict__ ei, int* __restrict__ deg, int E)
{
    int e = blockIdx.x * 256 + threadIdx.x;
    if (e < E) atomicAdd(&deg[ei[E + e]], 1);
}

// ---------------------------------------------------------------------------
// CSR build step 2: exclusive scan of deg -> off (N+1), duplicate into cursor.
// ---------------------------------------------------------------------------
__global__ __launch_bounds__(1024) void scan_kernel(
    const int* __restrict__ deg, int* __restrict__ off,
    int* __restrict__ cursor, int N)
{
    __shared__ int wsum[16];
    __shared__ int carry_s;
    int tid = threadIdx.x;
    int lane = tid & 63;
    int w = tid >> 6;
    if (tid == 0) carry_s = 0;
    __syncthreads();
    for (int base = 0; base < N; base += 1024) {
        int idx = base + tid;
        int x = (idx < N) ? deg[idx] : 0;
        int val = x;
#pragma unroll
        for (int s = 1; s < 64; s <<= 1) {
            int t = __shfl_up(val, s);
            if (lane >= s) val += t;
        }
        if (lane == 63) wsum[w] = val;
        __syncthreads();
        if (w == 0) {
            int t = (lane < 16) ? wsum[lane] : 0;
#pragma unroll
            for (int s = 1; s < 16; s <<= 1) {
                int u = __shfl_up(t, s);
                if (lane >= s) t += u;
            }
            if (lane < 16) wsum[lane] = t;  // inclusive wave totals
        }
        __syncthreads();
        int carry = carry_s;
        int wexcl = (w > 0) ? wsum[w - 1] : 0;
        int excl = carry + wexcl + (val - x);
        if (idx < N) { off[idx] = excl; cursor[idx] = excl; }
        __syncthreads();
        if (tid == 0) carry_s = carry + wsum[15];
        __syncthreads();
    }
    if (threadIdx.x == 0) off[N] = carry_s;
}

// ---------------------------------------------------------------------------
// CSR build step 3: scatter edge meta {src, ea0, ea1} into dst-grouped slots
// ---------------------------------------------------------------------------
__global__ __launch_bounds__(256) void scatter_edges(
    const int* __restrict__ ei, const float* __restrict__ ea,
    int* __restrict__ cursor, float4* __restrict__ meta, int E)
{
    int e = blockIdx.x * 256 + threadIdx.x;
    if (e >= E) return;
    int dst = ei[E + e];
    int pos = atomicAdd(&cursor[dst], 1);
    meta[pos] = make_float4(__int_as_float(ei[e]), ea[2 * e], ea[2 * e + 1], 0.f);
}

// ---------------------------------------------------------------------------
// Fused attention v4: one wave per dst node, 4 edges in flight, bf16 kv.
// Quarter (16 lanes) processes every 4th edge; lane ql covers 8 contiguous
// channels c8 = ql*8 (head = ql>>2, 4 lanes per head). Per edge: ONE 16B
// bf16 k-load + ONE 16B bf16 v-load per lane. QK reduce = shfl_xor 1,2.
// e-bias, q, softmax state all f32. Quarters merge via shfl_xor 16, 32.
// Sentinel m=-1e30 keeps empty quarters / deg-0 exact.
// ---------------------------------------------------------------------------
__global__ __launch_bounds__(256) void fused_attn(
    const float* __restrict__ q, const ushort* __restrict__ kv,
    const float* __restrict__ skip,
    const int* __restrict__ off, const float4* __restrict__ meta,
    const float* __restrict__ We, float* __restrict__ hout, int N)
{
    int wid = (int)((blockIdx.x * 256 + threadIdx.x) >> 6);  // dst node
    int lane = threadIdx.x & 63;
    if (wid >= N) return;
    int quarter = lane >> 4;         // 0..3: edge phase
    int ql = lane & 15;
    int c8 = ql * 8;                 // 8 channels, head = ql>>2

    float4 w0a = *(const float4*)(We + c8);
    float4 w0b = *(const float4*)(We + c8 + 4);
    float4 w1a = *(const float4*)(We + HD + c8);
    float4 w1b = *(const float4*)(We + HD + c8 + 4);
    float4 qa = *(const float4*)(q + (size_t)wid * HD + c8);
    float4 qb = *(const float4*)(q + (size_t)wid * HD + c8 + 4);

    float m = -1e30f, s = 0.f;
    float o[8];
#pragma unroll
    for (int i = 0; i < 8; ++i) o[i] = 0.f;

    int beg = off[wid], end = off[wid + 1];
    for (int j = beg + quarter; j < end; j += 4) {
        float4 md = meta[j];
        int src = __float_as_int(md.x);
        float e[8];
        e[0] = md.y * w0a.x + md.z * w1a.x;
        e[1] = md.y * w0a.y + md.z * w1a.y;
        e[2] = md.y * w0a.z + md.z * w1a.z;
        e[3] = md.y * w0a.w + md.z * w1a.w;
        e[4] = md.y * w0b.x + md.z * w1b.x;
        e[5] = md.y * w0b.y + md.z * w1b.y;
        e[6] = md.y * w0b.z + md.z * w1b.z;
        e[7] = md.y * w0b.w + md.z * w1b.w;
        short8 ku = *(const short8*)(kv + (size_t)src * 256 + c8);
        short8 vu = *(const short8*)(kv + (size_t)src * 256 + 128 + c8);
        float kf[8], vf[8];
#pragma unroll
        for (int i = 0; i < 8; ++i) {
            kf[i] = __uint_as_float(((unsigned)(ushort)ku[i]) << 16);
            vf[i] = __uint_as_float(((unsigned)(ushort)vu[i]) << 16);
        }
        float p = qa.x * (kf[0] + e[0]) + qa.y * (kf[1] + e[1])
                + qa.z * (kf[2] + e[2]) + qa.w * (kf[3] + e[3])
                + qb.x * (kf[4] + e[4]) + qb.y * (kf[5] + e[5])
                + qb.z * (kf[6] + e[6]) + qb.w * (kf[7] + e[7]);
        p += __shfl_xor(p, 1);
        p += __shfl_xor(p, 2);       // 4-lane head group reduce
        p *= 0.17677669529663687f;   // 1/sqrt(32)
        float mn = fmaxf(m, p);
        float sc = __expf(m - mn);
        float pe = __expf(p - mn);
        s = s * sc + pe;
#pragma unroll
        for (int i = 0; i < 8; ++i) o[i] = o[i] * sc + pe * (vf[i] + e[i]);
        m = mn;
    }

    // ---- merge quarter states: xor 16, then xor 32 ----
#pragma unroll
    for (int d = 16; d <= 32; d <<= 1) {
        float mo = __shfl_xor(m, d), so = __shfl_xor(s, d);
        float oo[8];
#pragma unroll
        for (int i = 0; i < 8; ++i) oo[i] = __shfl_xor(o[i], d);
        float mm = fmaxf(m, mo);
        float a = __expf(m - mm), b = __expf(mo - mm);
        s = s * a + so * b;
#pragma unroll
        for (int i = 0; i < 8; ++i) o[i] = o[i] * a + oo[i] * b;
        m = mm;
    }

    if (quarter == 0) {
        float inv = 1.f / (s + 1e-16f);      // deg==0: o=0 -> skip only
        float4 ska = *(const float4*)(skip + (size_t)wid * HD + c8);
        float4 skb = *(const float4*)(skip + (size_t)wid * HD + c8 + 4);
        float4 ha, hb;
        ha.x = leaky(o[0] * inv + ska.x);
        ha.y = leaky(o[1] * inv + ska.y);
        ha.z = leaky(o[2] * inv + ska.z);
        ha.w = leaky(o[3] * inv + ska.w);
        hb.x = leaky(o[4] * inv + skb.x);
        hb.y = leaky(o[5] * inv + skb.y);
        hb.z = leaky(o[6] * inv + skb.z);
        hb.w = leaky(o[7] * inv + skb.w);
        *(float4*)(hout + (size_t)wid * HD + c8) = ha;
        *(float4*)(hout + (size_t)wid * HD + c8 + 4) = hb;
    }
}

// ---------------------------------------------------------------------------
// emb = leaky(h @ W1 + b1)  (N x 128 @ 128 x 32).  v2: W1 staged in LDS
// (16 KB, broadcast reads), 64 rows/block x 4 col-groups, float4 h loads,
// 8 acc/thread, float4 stores. Same k-ascending order as the scalar version.
// ---------------------------------------------------------------------------
__global__ __launch_bounds__(256) void emb_kernel(
    const float* __restrict__ h, const float* __restrict__ W1,
    const float* __restrict__ b1, float* __restrict__ emb, int N)
{
    __shared__ float W1s[HD * CC];   // 16 KB
    int t = threadIdx.x;
#pragma unroll
    for (int i = 0; i < 4; ++i) {
        int idx = t + i * 256;       // float4 index 0..1023
        ((float4*)W1s)[idx] = ((const float4*)W1)[idx];
    }
    __syncthreads();

    int row = blockIdx.x * 64 + (t >> 2);
    int cg = (t & 3) * 8;            // 8 output cols
    if (row >= N) return;
    const float* hr = h + (size_t)row * HD;

    float acc[8];
#pragma unroll
    for (int c = 0; c < 8; ++c) acc[c] = 0.f;

    for (int k = 0; k < HD; k += 4) {
        float4 h4 = *(const float4*)(hr + k);
#pragma unroll
        for (int kk = 0; kk < 4; ++kk) {
            float hv = (kk == 0) ? h4.x : (kk == 1) ? h4.y : (kk == 2) ? h4.z : h4.w;
            const float* wrow = &W1s[(k + kk) * CC + cg];
            float4 w0 = *(const float4*)(wrow);
            float4 w1 = *(const float4*)(wrow + 4);
            acc[0] += hv * w0.x; acc[1] += hv * w0.y;
            acc[2] += hv * w0.z; acc[3] += hv * w0.w;
            acc[4] += hv * w1.x; acc[5] += hv * w1.y;
            acc[6] += hv * w1.z; acc[7] += hv * w1.w;
        }
    }

    float4 o0, o1;
    o0.x = leaky(acc[0] + b1[cg + 0]);
    o0.y = leaky(acc[1] + b1[cg + 1]);
    o0.z = leaky(acc[2] + b1[cg + 2]);
    o0.w = leaky(acc[3] + b1[cg + 3]);
    o1.x = leaky(acc[4] + b1[cg + 4]);
    o1.y = leaky(acc[5] + b1[cg + 5]);
    o1.z = leaky(acc[6] + b1[cg + 6]);
    o1.w = leaky(acc[7] + b1[cg + 7]);
    *(float4*)(emb + (size_t)row * CC + cg) = o0;
    *(float4*)(emb + (size_t)row * CC + cg + 4) = o1;
}

// ---------------------------------------------------------------------------
// logits = emb @ W2 + b2; out = log_softmax(logits) per row (8 cols).
// ---------------------------------------------------------------------------
__global__ __launch_bounds__(256) void logits_kernel(
    const float* __restrict__ emb, const float* __restrict__ W2,
    const float* __restrict__ b2, float* __restrict__ out, int N)
{
    int i = blockIdx.x * 256 + threadIdx.x;
    int row = i >> 3, col = i & 7;
    if (row >= N) return;
    const float* er = emb + (size_t)row * CC;
    float acc = b2[col];
#pragma unroll
    for (int k = 0; k < CC; ++k) acc += er[k] * W2[k * 8 + col];
    float mx = acc;
    mx = fmaxf(mx, __shfl_xor(mx, 1));
    mx = fmaxf(mx, __shfl_xor(mx, 2));
    mx = fmaxf(mx, __shfl_xor(mx, 4));
    float ex = expf(acc - mx);
    float sm = ex;
    sm += __shfl_xor(sm, 1);
    sm += __shfl_xor(sm, 2);
    sm += __shfl_xor(sm, 4);
    out[i] = acc - mx - logf(sm);
}

extern "C" void kernel_launch(void* const* d_in, const int* in_sizes, int n_in,
                              void* d_out, int out_size, void* d_ws, size_t ws_size,
                              hipStream_t stream)
{
    const float* x  = (const float*)d_in[0];
    const int*   ei = (const int*)d_in[1];
    const float* ea = (const float*)d_in[2];
    const float* Wq = (const float*)d_in[3];
    const float* bq = (const float*)d_in[4];
    const float* Wk = (const float*)d_in[5];
    const float* bk = (const float*)d_in[6];
    const float* Wv = (const float*)d_in[7];
    const float* bv = (const float*)d_in[8];
    const float* We = (const float*)d_in[9];
    const float* Ws = (const float*)d_in[10];
    const float* bs = (const float*)d_in[11];
    const float* W1 = (const float*)d_in[12];
    const float* b1 = (const float*)d_in[13];
    const float* W2 = (const float*)d_in[14];
    const float* b2 = (const float*)d_in[15];

    int N = in_sizes[0] / HD;
    int E = in_sizes[1] / 2;

    float* ws = (float*)d_ws;
    size_t nd = (size_t)N * HD;
    float* hbuf = ws;
    float* qbuf = ws + nd;
    float* kbuf = ws + 2 * nd;
    float* vbuf = ws + 3 * nd;
    float* sbuf = ws + 4 * nd;
    float4* meta = (float4*)(ws + 5 * nd);           // E float4
    int* deg    = (int*)(ws + 5 * nd + 4 * (size_t)E);
    int* off    = deg + N;                            // N+1
    int* cursor = off + N + 1;                        // N
    size_t frag_byte = (((5 * nd + 4 * (size_t)E) + (size_t)(3 * N + 1)) * 4 + 15)
                       & ~(size_t)15;
    ushort* Wfrag = (ushort*)((char*)d_ws + frag_byte);
    ushort* kvbuf = Wfrag + 2 * (size_t)WFRAG_HALF;   // N*256 ushorts (bf16 kv)

    int gemm_gx = (N + 63) / 64;
    int edge_gx = (E + 255) / 256;
    int attn_gx = (N + 3) / 4;

    // ---- CSR build + weight fragment conversion (once per call) ----
    hipMemsetAsync(deg, 0, (size_t)N * sizeof(int), stream);
    count_deg<<<edge_gx, 256, 0, stream>>>(ei, deg, E);
    scan_kernel<<<1, 1024, 0, stream>>>(deg, off, cursor, N);
    scatter_edges<<<edge_gx, 256, 0, stream>>>(ei, ea, cursor, meta, E);
    conv_w<<<(12 * 8 * 4 * 64 + 255) / 256, 256, 0, stream>>>(Wq, Wk, Wv, Ws, Wfrag);

    for (int l = 0; l < 3; ++l) {
        const float* cur = (l == 0) ? x : hbuf;
        const float* Wel = We + (size_t)l * 2 * HD;

        gemm4_mfma<<<dim3(gemm_gx, 2), 512, 0, stream>>>(
            cur, Wfrag,
            bq + (size_t)l * HD, bk + (size_t)l * HD,
            bv + (size_t)l * HD, bs + (size_t)l * HD,
            qbuf, kbuf, vbuf, sbuf, l, N);

        pack_kv<<<(N * 32 + 255) / 256, 256, 0, stream>>>(kbuf, vbuf, kvbuf, N);

        fused_attn<<<attn_gx, 256, 0, stream>>>(
            qbuf, kvbuf, sbuf, off, meta, Wel, hbuf, N);
    }

    // head: emb = leaky(h@W1+b1) -> reuse kbuf; logits+log_softmax -> d_out
    emb_kernel<<<gemm_gx, 256, 0, stream>>>(hbuf, W1, b1, kbuf, N);
    logits_kernel<<<(N * 8 + 255) / 256, 256, 0, stream>>>(kbuf, W2, b2, (float*)d_out, N);
}